// Round 1
// baseline (86.340 us; speedup 1.0000x reference)
//
#include <hip/hip_runtime.h>

#define CURIOSITY_COEF 0.1f
#define EPS_F 1e-8f

__global__ __launch_bounds__(256) void srnd_kernel(
    const float* __restrict__ rewards,
    const int*   __restrict__ corr,
    float*       __restrict__ out,
    int B)
{
    int g = blockIdx.x * blockDim.x + threadIdx.x;
    if (g >= B) return;

    // Each thread owns one group of 16. 4x float4 / int4 = 16B per lane per
    // instruction; a wave covers a contiguous 4KB span -> fully coalesced.
    const float4* r4 = reinterpret_cast<const float4*>(rewards) + (size_t)g * 4;
    const int4*   c4 = reinterpret_cast<const int4*>(corr)      + (size_t)g * 4;

    float rv[16];
    int   cv[16];
    #pragma unroll
    for (int q = 0; q < 4; ++q) {
        float4 rr = r4[q];
        int4   cc = c4[q];
        rv[q*4+0] = rr.x; rv[q*4+1] = rr.y; rv[q*4+2] = rr.z; rv[q*4+3] = rr.w;
        cv[q*4+0] = cc.x; cv[q*4+1] = cc.y; cv[q*4+2] = cc.z; cv[q*4+3] = cc.w;
    }

    // Masked min/max/count for the "correct" and "incorrect" strata.
    float minC =  INFINITY, maxC = -INFINITY;
    float minI =  INFINITY, maxI = -INFINITY;
    int   cntC = 0;
    #pragma unroll
    for (int i = 0; i < 16; ++i) {
        bool  c = (cv[i] != 0);
        float v = rv[i];
        minC = fminf(minC, c ? v :  INFINITY);
        maxC = fmaxf(maxC, c ? v : -INFINITY);
        minI = fminf(minI, c ?  INFINITY : v);
        maxI = fmaxf(maxI, c ? -INFINITY : v);
        cntC += c ? 1 : 0;
    }
    int cntI = 16 - cntC;

    // Hoist the division: (r - rmin) * (1 / (rmax - rmin + eps)).
    // Empty-stratum case gives inf/nan here, but an element only ever
    // selects the normalization of its OWN stratum (count >= 1), so the
    // poisoned operand is always the discarded side of the cndmask.
    float invC = 1.0f / (maxC - minC + EPS_F);
    float invI = 1.0f / (maxI - minI + EPS_F);

    float ov[16];
    #pragma unroll
    for (int i = 0; i < 16; ++i) {
        bool  c = (cv[i] != 0);
        float n;
        if (c)
            n = (cntC == 1) ? 0.5f : (rv[i] - minC) * invC;
        else
            n = (cntI == 1) ? 0.5f : (rv[i] - minI) * invI;
        ov[i] = c ? (CURIOSITY_COEF * n) : (-CURIOSITY_COEF * n);
    }

    float4* o4 = reinterpret_cast<float4*>(out) + (size_t)g * 4;
    #pragma unroll
    for (int q = 0; q < 4; ++q) {
        o4[q] = make_float4(ov[q*4+0], ov[q*4+1], ov[q*4+2], ov[q*4+3]);
    }
}

extern "C" void kernel_launch(void* const* d_in, const int* in_sizes, int n_in,
                              void* d_out, int out_size, void* d_ws, size_t ws_size,
                              hipStream_t stream) {
    const float* rewards = (const float*)d_in[0];
    const int*   corr    = (const int*)d_in[1];
    float*       out     = (float*)d_out;

    int N = in_sizes[0];
    int B = N / 16;  // group_size is fixed at 16 for this problem

    const int threads = 256;
    const int blocks  = (B + threads - 1) / threads;
    srnd_kernel<<<blocks, threads, 0, stream>>>(rewards, corr, out, B);
}

// Round 3
// 59.283 us; speedup vs baseline: 1.4564x; 1.4564x over previous
//
#include <hip/hip_runtime.h>

#define CURIOSITY_COEF 0.1f
#define EPS_F 1e-8f

typedef float f32x4 __attribute__((ext_vector_type(4)));
typedef int   i32x4 __attribute__((ext_vector_type(4)));

// 4 lanes per group of 16: lane q-in-cluster loads a contiguous float4/int4,
// so each wave-level load instruction covers one contiguous 1KiB span
// (16B/lane x 64 lanes) -- the max-coalescing pattern. Group-wide masked
// min/max/count are formed by a 2-step shfl_xor butterfly over each aligned
// 4-lane cluster.
__global__ __launch_bounds__(256) void srnd_kernel(
    const f32x4* __restrict__ r4,
    const i32x4* __restrict__ c4,
    f32x4*       __restrict__ o4,
    int Q)  // Q = number of quarter-groups = B*4
{
    int q = blockIdx.x * blockDim.x + threadIdx.x;
    if (q >= Q) return;

    f32x4 rr = r4[q];
    i32x4 cc = c4[q];
    float rv[4] = {rr.x, rr.y, rr.z, rr.w};
    int   cv[4] = {cc.x, cc.y, cc.z, cc.w};

    // Local masked min/max/count over this lane's 4 elements.
    float minC =  INFINITY, maxC = -INFINITY;
    float minI =  INFINITY, maxI = -INFINITY;
    int   cntC = 0;
    #pragma unroll
    for (int i = 0; i < 4; ++i) {
        bool  c = (cv[i] != 0);
        float v = rv[i];
        minC = fminf(minC, c ? v :  INFINITY);
        maxC = fmaxf(maxC, c ? v : -INFINITY);
        minI = fminf(minI, c ?  INFINITY : v);
        maxI = fmaxf(maxI, c ? -INFINITY : v);
        cntC += c ? 1 : 0;
    }

    // Butterfly reduce across the aligned 4-lane cluster (group = 4 lanes).
    #pragma unroll
    for (int m = 1; m <= 2; m <<= 1) {
        minC = fminf(minC, __shfl_xor(minC, m));
        maxC = fmaxf(maxC, __shfl_xor(maxC, m));
        minI = fminf(minI, __shfl_xor(minI, m));
        maxI = fmaxf(maxI, __shfl_xor(maxI, m));
        cntC +=            __shfl_xor(cntC, m);
    }
    int cntI = 16 - cntC;

    // Hoisted reciprocal of the denominator. Empty-stratum inf/nan only ever
    // lands on the discarded side of the per-element select (an element's own
    // stratum has count >= 1), so nothing poisonous propagates.
    float invC = 1.0f / (maxC - minC + EPS_F);
    float invI = 1.0f / (maxI - minI + EPS_F);

    f32x4 ov;
    #pragma unroll
    for (int i = 0; i < 4; ++i) {
        bool  c = (cv[i] != 0);
        float n;
        if (c)
            n = (cntC == 1) ? 0.5f : (rv[i] - minC) * invC;
        else
            n = (cntI == 1) ? 0.5f : (rv[i] - minI) * invI;
        ov[i] = c ? (CURIOSITY_COEF * n) : (-CURIOSITY_COEF * n);
    }

    // Non-temporal: the output is never re-read; keep it from evicting the
    // L3-resident input streams.
    __builtin_nontemporal_store(ov, &o4[q]);
}

extern "C" void kernel_launch(void* const* d_in, const int* in_sizes, int n_in,
                              void* d_out, int out_size, void* d_ws, size_t ws_size,
                              hipStream_t stream) {
    const float* rewards = (const float*)d_in[0];
    const int*   corr    = (const int*)d_in[1];
    float*       out     = (float*)d_out;

    int N = in_sizes[0];
    int Q = N / 4;  // quarter-groups (group_size = 16 -> 4 lanes/group)

    const int threads = 256;
    const int blocks  = (Q + threads - 1) / threads;
    srnd_kernel<<<blocks, threads, 0, stream>>>(
        reinterpret_cast<const f32x4*>(rewards),
        reinterpret_cast<const i32x4*>(corr),
        reinterpret_cast<f32x4*>(out), Q);
}